// Round 4
// baseline (909.739 us; speedup 1.0000x reference)
//
#include <hip/hip_runtime.h>
#include <hip/hip_bf16.h>
#include <cmath>

// ---------------------------------------------------------------------------
// Fused BN(+ELU) + GEMM: C[N,M] = act(A)[N,K] @ [B0|B1], where
// act(v) = stats ? elu(g*(v-mean)*rsqrt(var+eps)+b) : v.
// Writes act(A) to hout (residual) when stats != nullptr.
// Writes bf16 copy of C's first 64 cols to xlb when xlb != nullptr.
// ---------------------------------------------------------------------------
template<int K, int M, int ROWS>
__global__ __launch_bounds__(256)
void bn_gemm_kernel(const float* __restrict__ A, const float* __restrict__ B0,
                    const float* __restrict__ B1, float* __restrict__ C,
                    const float* __restrict__ stats, const float* __restrict__ g,
                    const float* __restrict__ b, float* __restrict__ hout,
                    __hip_bfloat16* __restrict__ xlb, int N, float invN)
{
    __shared__ float Bs[K * M];
    __shared__ float As[ROWS * K];
    __shared__ float sm[K], sv[K], sg[K], sb[K];
    if (stats != nullptr && threadIdx.x < K) {
        int f = threadIdx.x;
        float m   = stats[f] * invN;
        float var = stats[K + f] * invN - m * m;
        sm[f] = m;
        sv[f] = rsqrtf(var + 1e-5f);
        sg[f] = g[f];
        sb[f] = b[f];
    }
    for (int i = threadIdx.x; i < K * M; i += 256) {
        float v;
        if (B1 != nullptr) {
            int k = i / M, m = i - k * M;
            v = (m < M / 2) ? B0[k * (M / 2) + m] : B1[k * (M / 2) + (m - M / 2)];
        } else {
            v = B0[i];
        }
        Bs[i] = v;
    }
    __syncthreads();
    int row0 = blockIdx.x * ROWS;
    for (int i = threadIdx.x; i < ROWS * K; i += 256) {
        int r = row0 + i / K, k = i % K;
        float v = (r < N) ? A[(size_t)r * K + k] : 0.f;
        if (stats != nullptr) {
            float t = sg[k] * ((v - sm[k]) * sv[k]) + sb[k];
            v = (t > 0.f) ? t : expm1f(t);
            if (r < N) hout[(size_t)r * K + k] = v;
        }
        As[i] = v;
    }
    __syncthreads();
    for (int o = threadIdx.x; o < ROWS * M; o += 256) {
        int r = o / M, m = o - r * M;
        if (row0 + r >= N) continue;
        float acc = 0.f;
        #pragma unroll 16
        for (int k = 0; k < K; ++k) acc += As[r * K + k] * Bs[k * M + m];
        C[(size_t)(row0 + r) * M + m] = acc;
        if (xlb != nullptr && m < 64)
            xlb[(size_t)(row0 + r) * 64 + m] = __float2bfloat16(acc);
    }
}

// ---------------------------------------------------------------------------
// CSR build: histogram, 3-phase parallel scan, scatter.
// ---------------------------------------------------------------------------
__global__ __launch_bounds__(256)
void hist_kernel(const int* __restrict__ dsts, int* __restrict__ deg, int E)
{
    int e = blockIdx.x * 256 + threadIdx.x;
    if (e < E) atomicAdd(&deg[dsts[e]], 1);
}

__global__ __launch_bounds__(256)
void scan_partials_kernel(const int* __restrict__ deg, int* __restrict__ part, int N)
{
    int base = blockIdx.x * 2048;
    int s = 0;
    for (int i = threadIdx.x; i < 2048; i += 256) {
        int idx = base + i;
        if (idx < N) s += deg[idx];
    }
    #pragma unroll
    for (int off = 32; off > 0; off >>= 1) s += __shfl_xor(s, off);
    __shared__ int ws[4];
    if ((threadIdx.x & 63) == 0) ws[threadIdx.x >> 6] = s;
    __syncthreads();
    if (threadIdx.x == 0) part[blockIdx.x] = ws[0] + ws[1] + ws[2] + ws[3];
}

__global__ __launch_bounds__(256)
void scan_scan_kernel(int* __restrict__ part, int nb)
{
    __shared__ int buf[256];
    int v = (threadIdx.x < nb) ? part[threadIdx.x] : 0;
    buf[threadIdx.x] = v;
    __syncthreads();
    for (int off = 1; off < 256; off <<= 1) {
        int t = (threadIdx.x >= off) ? buf[threadIdx.x - off] : 0;
        __syncthreads();
        buf[threadIdx.x] += t;
        __syncthreads();
    }
    if (threadIdx.x < nb) part[threadIdx.x] = buf[threadIdx.x] - v;  // exclusive
}

__global__ __launch_bounds__(256)
void scan_final_kernel(const int* __restrict__ deg, const int* __restrict__ part,
                       int* __restrict__ row_ptr, int* __restrict__ cursor, int N, int E)
{
    int base = blockIdx.x * 2048;
    int idx0 = base + threadIdx.x * 8;
    int v[8];
    int s = 0;
    #pragma unroll
    for (int d = 0; d < 8; ++d) {
        int idx = idx0 + d;
        v[d] = (idx < N) ? deg[idx] : 0;
        s += v[d];
    }
    __shared__ int buf[256];
    buf[threadIdx.x] = s;
    __syncthreads();
    for (int off = 1; off < 256; off <<= 1) {
        int t = (threadIdx.x >= off) ? buf[threadIdx.x - off] : 0;
        __syncthreads();
        buf[threadIdx.x] += t;
        __syncthreads();
    }
    int excl = buf[threadIdx.x] - s + part[blockIdx.x];
    #pragma unroll
    for (int d = 0; d < 8; ++d) {
        int idx = idx0 + d;
        if (idx < N) { row_ptr[idx] = excl; cursor[idx] = excl; }
        excl += v[d];
    }
    if (blockIdx.x == 0 && threadIdx.x == 0) row_ptr[N] = E;
}

__global__ __launch_bounds__(256)
void scatter_kernel(const int* __restrict__ srcs, const int* __restrict__ dsts,
                    int* __restrict__ cursor, int* __restrict__ col, int E)
{
    int e = blockIdx.x * 256 + threadIdx.x;
    if (e < E) {
        int pos = atomicAdd(&cursor[dsts[e]], 1);
        col[pos] = srcs[e];
    }
}

// ---------------------------------------------------------------------------
// Node-centric GATv2 + residual + BN-stats. One wave per node, lane=feature.
// xl gathered from bf16 table (L2-resident); xr/hres fp32 coalesced.
// ---------------------------------------------------------------------------
__global__ __launch_bounds__(256)
void gat_node_kernel(const int* __restrict__ row_ptr, const int* __restrict__ col,
                     const __hip_bfloat16* __restrict__ xlb,
                     const float* __restrict__ xlr, const float* __restrict__ att,
                     const float* __restrict__ hres, float* __restrict__ z,
                     float* __restrict__ stats, int N)
{
    int lane = threadIdx.x & 63;
    int wid  = threadIdx.x >> 6;
    float attv = att[lane];
    float s = 0.f, s2 = 0.f;
    for (int n = blockIdx.x * 4 + wid; n < N; n += gridDim.x * 4) {
        float xr = xlr[(size_t)n * 128 + 64 + lane];
        int beg = row_ptr[n], end = row_ptr[n + 1];
        float acc = 0.f, den = 0.f;
        int j = beg;
        for (; j + 8 <= end; j += 8) {
            float xl[8];
            #pragma unroll
            for (int d = 0; d < 8; ++d)
                xl[d] = __bfloat162float(xlb[(size_t)col[j + d] * 64 + lane]);
            #pragma unroll
            for (int d = 0; d < 8; ++d) {
                float sum = xl[d] + xr;
                float lr = (sum > 0.f) ? sum : 0.2f * sum;
                float t = lr * attv;
                t += __shfl_xor(t, 1);
                t += __shfl_xor(t, 2);
                t += __shfl_xor(t, 4);
                float ex = __expf(t);
                acc = fmaf(ex, xl[d], acc);
                den += ex;
            }
        }
        for (; j < end; ++j) {
            float xl = __bfloat162float(xlb[(size_t)col[j] * 64 + lane]);
            float sum = xl + xr;
            float lr = (sum > 0.f) ? sum : 0.2f * sum;
            float t = lr * attv;
            t += __shfl_xor(t, 1);
            t += __shfl_xor(t, 2);
            t += __shfl_xor(t, 4);
            float ex = __expf(t);
            acc = fmaf(ex, xl, acc);
            den += ex;
        }
        float v = acc / (den + 1e-16f) + hres[(size_t)n * 64 + lane];
        z[(size_t)n * 64 + lane] = v;
        s += v;
        s2 += v * v;
    }
    __shared__ float ls[2][4][64];
    ls[0][wid][lane] = s;
    ls[1][wid][lane] = s2;
    __syncthreads();
    if (threadIdx.x < 128) {
        int which = threadIdx.x >> 6;
        int f = threadIdx.x & 63;
        float a = ls[which][0][f] + ls[which][1][f] + ls[which][2][f] + ls[which][3][f];
        unsafeAtomicAdd(&stats[which * 64 + f], a);
    }
}

// ---------------------------------------------------------------------------
// BN-stats over a plain array (pre-layer only).
// ---------------------------------------------------------------------------
__global__ __launch_bounds__(256)
void stats_kernel(const float* __restrict__ y, float* __restrict__ stats, int N)
{
    int f  = threadIdx.x & 63;
    int rg = threadIdx.x >> 6;
    float s = 0.f, s2 = 0.f;
    for (int r = blockIdx.x * 4 + rg; r < N; r += gridDim.x * 4) {
        float v = y[(size_t)r * 64 + f];
        s += v;
        s2 += v * v;
    }
    __shared__ float ls[2][4][64];
    ls[0][rg][f] = s;
    ls[1][rg][f] = s2;
    __syncthreads();
    if (threadIdx.x < 128) {
        int which = threadIdx.x >> 6;
        float a = ls[which][0][f] + ls[which][1][f] + ls[which][2][f] + ls[which][3][f];
        unsafeAtomicAdd(&stats[which * 64 + f], a);
    }
}

// ---------------------------------------------------------------------------
// MLP head with fused BN+ELU on the input: 64->48->32->16->2.
// ---------------------------------------------------------------------------
__global__ __launch_bounds__(256)
void mlp_kernel(const float* __restrict__ z, const float* __restrict__ stats,
                const float* __restrict__ g, const float* __restrict__ b,
                const float* __restrict__ W1, const float* __restrict__ B1,
                const float* __restrict__ W2, const float* __restrict__ B2,
                const float* __restrict__ W3, const float* __restrict__ B3,
                const float* __restrict__ W4, const float* __restrict__ B4,
                float* __restrict__ out, int N, float invN)
{
    __shared__ float w1[64 * 48], w2[48 * 32], w3[32 * 16], w4[16 * 2];
    __shared__ float bb1[48], bb2[32], bb3[16], bb4[2];
    __shared__ float sm[64], sv[64], sg[64], sb[64];
    for (int i = threadIdx.x; i < 64 * 48; i += 256) w1[i] = W1[i];
    for (int i = threadIdx.x; i < 48 * 32; i += 256) w2[i] = W2[i];
    for (int i = threadIdx.x; i < 32 * 16; i += 256) w3[i] = W3[i];
    for (int i = threadIdx.x; i < 16 * 2;  i += 256) w4[i] = W4[i];
    if (threadIdx.x < 48) bb1[threadIdx.x] = B1[threadIdx.x];
    if (threadIdx.x < 32) bb2[threadIdx.x] = B2[threadIdx.x];
    if (threadIdx.x < 16) bb3[threadIdx.x] = B3[threadIdx.x];
    if (threadIdx.x < 2)  bb4[threadIdx.x] = B4[threadIdx.x];
    if (threadIdx.x >= 64 && threadIdx.x < 128) {
        int f = threadIdx.x - 64;
        float m   = stats[f] * invN;
        float var = stats[64 + f] * invN - m * m;
        sm[f] = m;
        sv[f] = rsqrtf(var + 1e-5f);
        sg[f] = g[f];
        sb[f] = b[f];
    }
    __syncthreads();
    int n = blockIdx.x * 256 + threadIdx.x;
    if (n >= N) return;
    float a[64];
    const float4* hp = (const float4*)(z + (size_t)n * 64);
    #pragma unroll
    for (int i = 0; i < 16; ++i) {
        float4 v = hp[i];
        a[4 * i] = v.x; a[4 * i + 1] = v.y; a[4 * i + 2] = v.z; a[4 * i + 3] = v.w;
    }
    #pragma unroll
    for (int k = 0; k < 64; ++k) {
        float t = sg[k] * ((a[k] - sm[k]) * sv[k]) + sb[k];
        a[k] = (t > 0.f) ? t : expm1f(t);
    }
    float t1[48];
    for (int j = 0; j < 48; ++j) {
        float acc = bb1[j];
        #pragma unroll
        for (int k = 0; k < 64; ++k) acc += a[k] * w1[k * 48 + j];
        t1[j] = (acc > 0.f) ? acc : expm1f(acc);
    }
    float t2[32];
    for (int j = 0; j < 32; ++j) {
        float acc = bb2[j];
        #pragma unroll
        for (int k = 0; k < 48; ++k) acc += t1[k] * w2[k * 32 + j];
        t2[j] = (acc > 0.f) ? acc : expm1f(acc);
    }
    float t3[16];
    for (int j = 0; j < 16; ++j) {
        float acc = bb3[j];
        #pragma unroll
        for (int k = 0; k < 32; ++k) acc += t2[k] * w3[k * 16 + j];
        t3[j] = (acc > 0.f) ? acc : expm1f(acc);
    }
    float o0 = bb4[0], o1 = bb4[1];
    #pragma unroll
    for (int k = 0; k < 16; ++k) {
        o0 += t3[k] * w4[k * 2 + 0];
        o1 += t3[k] * w4[k * 2 + 1];
    }
    out[(size_t)n * 2 + 0] = o0;
    out[(size_t)n * 2 + 1] = o1;
}

// ---------------------------------------------------------------------------
extern "C" void kernel_launch(void* const* d_in, const int* in_sizes, int n_in,
                              void* d_out, int out_size, void* d_ws, size_t ws_size,
                              hipStream_t stream)
{
    const float* x    = (const float*)d_in[0];
    const int*   ei   = (const int*)d_in[1];
    const float* Wpre = (const float*)d_in[2];
    const float* g0   = (const float*)d_in[3];
    const float* b0   = (const float*)d_in[4];

    const int N = in_sizes[0] / 128;
    const int E = in_sizes[1] / 2;
    const float invN = 1.f / (float)N;

    float* ws      = (float*)d_ws;
    float* h       = ws;                      // N*64
    float* xlr     = h + (size_t)N * 64;      // N*128
    float* z       = xlr + (size_t)N * 128;   // N*64
    float* stats   = z + (size_t)N * 64;      // 5*128
    int*   deg     = (int*)(stats + 5 * 128); // N
    int*   row_ptr = deg + N;                 // N+1
    int*   cursor  = row_ptr + N + 1;         // N
    int*   part    = cursor + N;              // 256
    int*   col     = part + 256;              // E
    __hip_bfloat16* xlb = (__hip_bfloat16*)(col + E);  // N*64

    const int* srcs = ei;
    const int* dsts = ei + E;
    const int nb = (N + 2047) / 2048;

    // ---- CSR build ----
    hipMemsetAsync(deg, 0, (size_t)N * sizeof(int), stream);
    hipMemsetAsync(stats, 0, 5 * 128 * sizeof(float), stream);
    hist_kernel<<<(E + 255) / 256, 256, 0, stream>>>(dsts, deg, E);
    scan_partials_kernel<<<nb, 256, 0, stream>>>(deg, part, N);
    scan_scan_kernel<<<1, 256, 0, stream>>>(part, nb);
    scan_final_kernel<<<nb, 256, 0, stream>>>(deg, part, row_ptr, cursor, N, E);
    scatter_kernel<<<(E + 255) / 256, 256, 0, stream>>>(srcs, dsts, cursor, col, E);

    // ---- pre-layer: z = x @ Wpre ; stats0 ----
    bn_gemm_kernel<128, 64, 16><<<(N + 15) / 16, 256, 0, stream>>>(
        x, Wpre, nullptr, z, nullptr, nullptr, nullptr, nullptr, nullptr, N, invN);
    stats_kernel<<<1024, 256, 0, stream>>>(z, stats, N);

    // ---- 4 GATv2 layers ----
    for (int l = 0; l < 4; ++l) {
        const float* Wl  = (const float*)d_in[5 + 5 * l + 0];
        const float* Wr  = (const float*)d_in[5 + 5 * l + 1];
        const float* att = (const float*)d_in[5 + 5 * l + 2];
        const float* gp = (l == 0) ? g0 : (const float*)d_in[5 + 5 * (l - 1) + 3];
        const float* bp = (l == 0) ? b0 : (const float*)d_in[5 + 5 * (l - 1) + 4];
        float* statsp = stats + 128 * l;

        bn_gemm_kernel<64, 128, 16><<<(N + 15) / 16, 256, 0, stream>>>(
            z, Wl, Wr, xlr, statsp, gp, bp, h, xlb, N, invN);
        gat_node_kernel<<<2560, 256, 0, stream>>>(
            row_ptr, col, xlb, xlr, att, h, z, stats + 128 * (l + 1), N);
    }

    // ---- MLP head (BN4 fused) ----
    const float* g4  = (const float*)d_in[23];
    const float* b4  = (const float*)d_in[24];
    const float* Wp1 = (const float*)d_in[25]; const float* bp1 = (const float*)d_in[26];
    const float* Wp2 = (const float*)d_in[27]; const float* bp2 = (const float*)d_in[28];
    const float* Wp3 = (const float*)d_in[29]; const float* bp3 = (const float*)d_in[30];
    const float* Wp4 = (const float*)d_in[31]; const float* bp4 = (const float*)d_in[32];
    mlp_kernel<<<(N + 255) / 256, 256, 0, stream>>>(
        z, stats + 512, g4, b4, Wp1, bp1, Wp2, bp2, Wp3, bp3, Wp4, bp4,
        (float*)d_out, N, invN);
}

// Round 5
// 784.795 us; speedup vs baseline: 1.1592x; 1.1592x over previous
//
#include <hip/hip_runtime.h>
#include <hip/hip_bf16.h>
#include <cmath>

__device__ inline void unpack_bf2(unsigned int u, float& lo, float& hi) {
    union { unsigned int i; float f; } a, b;
    a.i = u << 16; b.i = u & 0xffff0000u;
    lo = a.f; hi = b.f;
}
__device__ inline unsigned short bf16_bits(float x) {
    __hip_bfloat16 v = __float2bfloat16(x);
    return *reinterpret_cast<unsigned short*>(&v);
}

// ---------------------------------------------------------------------------
// Fused BN(+ELU) + GEMM. A[N,K] -> act -> @ [B0|B1] [K,M].
// If C != null: write fp32 C[N,M] (pre-layer).
// Else: write cols 0..63 as bf16 to xlb[N,64], cols 64..127 as f32 to xr[N,64].
// When stats != null, act = elu(bn(...)) and act(A) also written to hout.
// ---------------------------------------------------------------------------
template<int K, int M, int ROWS>
__global__ __launch_bounds__(256)
void bn_gemm_kernel(const float* __restrict__ A, const float* __restrict__ B0,
                    const float* __restrict__ B1, float* __restrict__ C,
                    __hip_bfloat16* __restrict__ xlb, float* __restrict__ xr_arr,
                    const float* __restrict__ stats, const float* __restrict__ g,
                    const float* __restrict__ b, float* __restrict__ hout,
                    int N, float invN)
{
    constexpr int TM = ROWS * M / 256;
    __shared__ float Bs[K * M];
    __shared__ float As[ROWS * (K + 1)];
    __shared__ float sm[K], sv[K], sg[K], sb[K];
    if (stats != nullptr && threadIdx.x < K) {
        int f = threadIdx.x;
        float m   = stats[f] * invN;
        float var = stats[K + f] * invN - m * m;
        sm[f] = m;
        sv[f] = rsqrtf(var + 1e-5f);
        sg[f] = g[f];
        sb[f] = b[f];
    }
    for (int i = threadIdx.x; i < K * M; i += 256) {
        float v;
        if (B1 != nullptr) {
            int k = i / M, m = i - k * M;
            v = (m < M / 2) ? B0[k * (M / 2) + m] : B1[k * (M / 2) + (m - M / 2)];
        } else {
            v = B0[i];
        }
        Bs[i] = v;
    }
    __syncthreads();
    int row0 = blockIdx.x * ROWS;
    for (int i = threadIdx.x; i < ROWS * K; i += 256) {
        int rr = i / K, kk = i - rr * K;
        int r = row0 + rr;
        float v = (r < N) ? A[(size_t)r * K + kk] : 0.f;
        if (stats != nullptr) {
            float t = sg[kk] * ((v - sm[kk]) * sv[kk]) + sb[kk];
            v = (t > 0.f) ? t : expm1f(t);
            if (r < N) hout[(size_t)r * K + kk] = v;
        }
        As[rr * (K + 1) + kk] = v;
    }
    __syncthreads();
    int r  = threadIdx.x / (M / TM);
    int m0 = (threadIdx.x % (M / TM)) * TM;
    int row = row0 + r;
    float acc[TM];
    #pragma unroll
    for (int i = 0; i < TM; ++i) acc[i] = 0.f;
    const float* as = &As[r * (K + 1)];
    for (int k = 0; k < K; ++k) {
        float a = as[k];
        #pragma unroll
        for (int mm = 0; mm < TM; mm += 4) {
            float4 bv = *(const float4*)&Bs[k * M + m0 + mm];
            acc[mm + 0] = fmaf(a, bv.x, acc[mm + 0]);
            acc[mm + 1] = fmaf(a, bv.y, acc[mm + 1]);
            acc[mm + 2] = fmaf(a, bv.z, acc[mm + 2]);
            acc[mm + 3] = fmaf(a, bv.w, acc[mm + 3]);
        }
    }
    if (row >= N) return;
    if (C != nullptr) {
        #pragma unroll
        for (int mm = 0; mm < TM; mm += 4) {
            float4 o = make_float4(acc[mm], acc[mm + 1], acc[mm + 2], acc[mm + 3]);
            *(float4*)&C[(size_t)row * M + m0 + mm] = o;
        }
    } else {
        if (m0 < 64) {
            unsigned int u[TM / 2];
            #pragma unroll
            for (int i = 0; i < TM / 2; ++i)
                u[i] = (unsigned int)bf16_bits(acc[2 * i]) |
                       ((unsigned int)bf16_bits(acc[2 * i + 1]) << 16);
            *(uint4*)(xlb + (size_t)row * 64 + m0) =
                make_uint4(u[0], u[1], u[2], u[3]);
        } else {
            #pragma unroll
            for (int mm = 0; mm < TM; mm += 4) {
                float4 o = make_float4(acc[mm], acc[mm + 1], acc[mm + 2], acc[mm + 3]);
                *(float4*)&xr_arr[(size_t)row * 64 + (m0 - 64) + mm] = o;
            }
        }
    }
}

// ---------------------------------------------------------------------------
// CSR build: histogram, 3-phase parallel scan, scatter.
// ---------------------------------------------------------------------------
__global__ __launch_bounds__(256)
void hist_kernel(const int* __restrict__ dsts, int* __restrict__ deg, int E)
{
    int e = blockIdx.x * 256 + threadIdx.x;
    if (e < E) atomicAdd(&deg[dsts[e]], 1);
}

__global__ __launch_bounds__(256)
void scan_partials_kernel(const int* __restrict__ deg, int* __restrict__ part, int N)
{
    int base = blockIdx.x * 2048;
    int s = 0;
    for (int i = threadIdx.x; i < 2048; i += 256) {
        int idx = base + i;
        if (idx < N) s += deg[idx];
    }
    #pragma unroll
    for (int off = 32; off > 0; off >>= 1) s += __shfl_xor(s, off);
    __shared__ int ws[4];
    if ((threadIdx.x & 63) == 0) ws[threadIdx.x >> 6] = s;
    __syncthreads();
    if (threadIdx.x == 0) part[blockIdx.x] = ws[0] + ws[1] + ws[2] + ws[3];
}

__global__ __launch_bounds__(256)
void scan_scan_kernel(int* __restrict__ part, int nb)
{
    __shared__ int buf[256];
    int v = (threadIdx.x < nb) ? part[threadIdx.x] : 0;
    buf[threadIdx.x] = v;
    __syncthreads();
    for (int off = 1; off < 256; off <<= 1) {
        int t = (threadIdx.x >= off) ? buf[threadIdx.x - off] : 0;
        __syncthreads();
        buf[threadIdx.x] += t;
        __syncthreads();
    }
    if (threadIdx.x < nb) part[threadIdx.x] = buf[threadIdx.x] - v;  // exclusive
}

__global__ __launch_bounds__(256)
void scan_final_kernel(const int* __restrict__ deg, const int* __restrict__ part,
                       int* __restrict__ row_ptr, int* __restrict__ cursor, int N, int E)
{
    int base = blockIdx.x * 2048;
    int idx0 = base + threadIdx.x * 8;
    int v[8];
    int s = 0;
    #pragma unroll
    for (int d = 0; d < 8; ++d) {
        int idx = idx0 + d;
        v[d] = (idx < N) ? deg[idx] : 0;
        s += v[d];
    }
    __shared__ int buf[256];
    buf[threadIdx.x] = s;
    __syncthreads();
    for (int off = 1; off < 256; off <<= 1) {
        int t = (threadIdx.x >= off) ? buf[threadIdx.x - off] : 0;
        __syncthreads();
        buf[threadIdx.x] += t;
        __syncthreads();
    }
    int excl = buf[threadIdx.x] - s + part[blockIdx.x];
    #pragma unroll
    for (int d = 0; d < 8; ++d) {
        int idx = idx0 + d;
        if (idx < N) { row_ptr[idx] = excl; cursor[idx] = excl; }
        excl += v[d];
    }
    if (blockIdx.x == 0 && threadIdx.x == 0) row_ptr[N] = E;
}

__global__ __launch_bounds__(256)
void scatter_kernel(const int* __restrict__ srcs, const int* __restrict__ dsts,
                    int* __restrict__ cursor, int* __restrict__ col, int E)
{
    int e = blockIdx.x * 256 + threadIdx.x;
    if (e < E) {
        int pos = atomicAdd(&cursor[dsts[e]], 1);
        col[pos] = srcs[e];
    }
}

// ---------------------------------------------------------------------------
// Node-centric GATv2, (edge,head)-per-lane layout.
// lane = eg*8+h: eg = edge slot (8 edges/chunk), h = head; lane owns all 8 c.
// One dwordx4 per chunk loads xl for 8 edges; logit is lane-local (no shfl).
// Cross-lane reduce (stride 8/16/32) once per node. Residual+BN-stats fused.
// ---------------------------------------------------------------------------
__global__ __launch_bounds__(256)
void gat_node_kernel(const int* __restrict__ row_ptr, const int* __restrict__ col,
                     const __hip_bfloat16* __restrict__ xlb,
                     const float* __restrict__ xr_arr, const float* __restrict__ att,
                     const float* __restrict__ hres, float* __restrict__ z,
                     float* __restrict__ stats, int N)
{
    int lane = threadIdx.x & 63;
    int wid  = threadIdx.x >> 6;
    int eg   = lane >> 3;
    int h    = lane & 7;
    float attv[8];
    {
        const float4* a4 = (const float4*)(att + h * 8);
        float4 a0 = a4[0], a1 = a4[1];
        attv[0]=a0.x; attv[1]=a0.y; attv[2]=a0.z; attv[3]=a0.w;
        attv[4]=a1.x; attv[5]=a1.y; attv[6]=a1.z; attv[7]=a1.w;
    }
    float fs[8], fs2[8];
    #pragma unroll
    for (int c = 0; c < 8; ++c) { fs[c] = 0.f; fs2[c] = 0.f; }

    for (int n = blockIdx.x * 4 + wid; n < N; n += gridDim.x * 4) {
        float xr[8];
        {
            const float4* x4 = (const float4*)(xr_arr + (size_t)n * 64 + h * 8);
            float4 r0 = x4[0], r1 = x4[1];
            xr[0]=r0.x; xr[1]=r0.y; xr[2]=r0.z; xr[3]=r0.w;
            xr[4]=r1.x; xr[5]=r1.y; xr[6]=r1.z; xr[7]=r1.w;
        }
        int beg = row_ptr[n], end = row_ptr[n + 1];
        float acc[8];
        #pragma unroll
        for (int c = 0; c < 8; ++c) acc[c] = 0.f;
        float den = 0.f;
        if (beg < end) {
            int je = beg + eg;
            int idx = col[je < end ? je : end - 1];
            uint4 p = *(const uint4*)(xlb + (size_t)idx * 64 + h * 8);
            for (int j = beg; j < end; j += 8) {
                // prefetch next chunk
                int jn = j + 8 + eg;
                int idxn = col[jn < end ? jn : end - 1];
                uint4 pn = *(const uint4*)(xlb + (size_t)idxn * 64 + h * 8);
                // unpack current 8 xl values
                float xl[8];
                unpack_bf2(p.x, xl[0], xl[1]);
                unpack_bf2(p.y, xl[2], xl[3]);
                unpack_bf2(p.z, xl[4], xl[5]);
                unpack_bf2(p.w, xl[6], xl[7]);
                float logit = 0.f;
                #pragma unroll
                for (int c = 0; c < 8; ++c) {
                    float sum = xl[c] + xr[c];
                    float lr = fmaf(0.8f, fmaxf(sum, 0.f), 0.2f * sum);
                    logit = fmaf(lr, attv[c], logit);
                }
                float ex = ((j + eg) < end) ? __expf(logit) : 0.f;
                #pragma unroll
                for (int c = 0; c < 8; ++c) acc[c] = fmaf(ex, xl[c], acc[c]);
                den += ex;
                p = pn;
            }
        }
        #pragma unroll
        for (int off = 8; off <= 32; off <<= 1) {
            den += __shfl_xor(den, off);
            #pragma unroll
            for (int c = 0; c < 8; ++c) acc[c] += __shfl_xor(acc[c], off);
        }
        if (eg == 0) {  // lanes 0..7, h == lane
            float inv = 1.f / (den + 1e-16f);
            const float4* hr4 = (const float4*)(hres + (size_t)n * 64 + h * 8);
            float4 h0 = hr4[0], h1 = hr4[1];
            float hv[8] = {h0.x, h0.y, h0.z, h0.w, h1.x, h1.y, h1.z, h1.w};
            float v[8];
            #pragma unroll
            for (int c = 0; c < 8; ++c) {
                v[c] = acc[c] * inv + hv[c];
                fs[c] += v[c];
                fs2[c] += v[c] * v[c];
            }
            float4* z4 = (float4*)(z + (size_t)n * 64 + h * 8);
            z4[0] = make_float4(v[0], v[1], v[2], v[3]);
            z4[1] = make_float4(v[4], v[5], v[6], v[7]);
        }
    }
    __shared__ float lstat[2][4][64];
    if (eg == 0) {
        #pragma unroll
        for (int c = 0; c < 8; ++c) {
            lstat[0][wid][h * 8 + c] = fs[c];
            lstat[1][wid][h * 8 + c] = fs2[c];
        }
    }
    __syncthreads();
    if (threadIdx.x < 128) {
        int which = threadIdx.x >> 6;
        int f = threadIdx.x & 63;
        float a = lstat[which][0][f] + lstat[which][1][f] +
                  lstat[which][2][f] + lstat[which][3][f];
        unsafeAtomicAdd(&stats[which * 64 + f], a);
    }
}

// ---------------------------------------------------------------------------
// BN-stats over a plain array (pre-layer only).
// ---------------------------------------------------------------------------
__global__ __launch_bounds__(256)
void stats_kernel(const float* __restrict__ y, float* __restrict__ stats, int N)
{
    int f  = threadIdx.x & 63;
    int rg = threadIdx.x >> 6;
    float s = 0.f, s2 = 0.f;
    for (int r = blockIdx.x * 4 + rg; r < N; r += gridDim.x * 4) {
        float v = y[(size_t)r * 64 + f];
        s += v;
        s2 += v * v;
    }
    __shared__ float ls[2][4][64];
    ls[0][rg][f] = s;
    ls[1][rg][f] = s2;
    __syncthreads();
    if (threadIdx.x < 128) {
        int which = threadIdx.x >> 6;
        float a = ls[which][0][f] + ls[which][1][f] + ls[which][2][f] + ls[which][3][f];
        unsafeAtomicAdd(&stats[which * 64 + f], a);
    }
}

// ---------------------------------------------------------------------------
// MLP head with fused BN+ELU on the input: 64->48->32->16->2.
// ---------------------------------------------------------------------------
__global__ __launch_bounds__(256)
void mlp_kernel(const float* __restrict__ z, const float* __restrict__ stats,
                const float* __restrict__ g, const float* __restrict__ b,
                const float* __restrict__ W1, const float* __restrict__ B1,
                const float* __restrict__ W2, const float* __restrict__ B2,
                const float* __restrict__ W3, const float* __restrict__ B3,
                const float* __restrict__ W4, const float* __restrict__ B4,
                float* __restrict__ out, int N, float invN)
{
    __shared__ float w1[64 * 48], w2[48 * 32], w3[32 * 16], w4[16 * 2];
    __shared__ float bb1[48], bb2[32], bb3[16], bb4[2];
    __shared__ float sm[64], sv[64], sg[64], sb[64];
    for (int i = threadIdx.x; i < 64 * 48; i += 256) w1[i] = W1[i];
    for (int i = threadIdx.x; i < 48 * 32; i += 256) w2[i] = W2[i];
    for (int i = threadIdx.x; i < 32 * 16; i += 256) w3[i] = W3[i];
    for (int i = threadIdx.x; i < 16 * 2;  i += 256) w4[i] = W4[i];
    if (threadIdx.x < 48) bb1[threadIdx.x] = B1[threadIdx.x];
    if (threadIdx.x < 32) bb2[threadIdx.x] = B2[threadIdx.x];
    if (threadIdx.x < 16) bb3[threadIdx.x] = B3[threadIdx.x];
    if (threadIdx.x < 2)  bb4[threadIdx.x] = B4[threadIdx.x];
    if (threadIdx.x >= 64 && threadIdx.x < 128) {
        int f = threadIdx.x - 64;
        float m   = stats[f] * invN;
        float var = stats[64 + f] * invN - m * m;
        sm[f] = m;
        sv[f] = rsqrtf(var + 1e-5f);
        sg[f] = g[f];
        sb[f] = b[f];
    }
    __syncthreads();
    int n = blockIdx.x * 256 + threadIdx.x;
    if (n >= N) return;
    float a[64];
    const float4* hp = (const float4*)(z + (size_t)n * 64);
    #pragma unroll
    for (int i = 0; i < 16; ++i) {
        float4 v = hp[i];
        a[4 * i] = v.x; a[4 * i + 1] = v.y; a[4 * i + 2] = v.z; a[4 * i + 3] = v.w;
    }
    #pragma unroll
    for (int k = 0; k < 64; ++k) {
        float t = sg[k] * ((a[k] - sm[k]) * sv[k]) + sb[k];
        a[k] = (t > 0.f) ? t : expm1f(t);
    }
    float t1[48];
    for (int j = 0; j < 48; ++j) {
        float acc = bb1[j];
        #pragma unroll
        for (int k = 0; k < 64; ++k) acc += a[k] * w1[k * 48 + j];
        t1[j] = (acc > 0.f) ? acc : expm1f(acc);
    }
    float t2[32];
    for (int j = 0; j < 32; ++j) {
        float acc = bb2[j];
        #pragma unroll
        for (int k = 0; k < 48; ++k) acc += t1[k] * w2[k * 32 + j];
        t2[j] = (acc > 0.f) ? acc : expm1f(acc);
    }
    float t3[16];
    for (int j = 0; j < 16; ++j) {
        float acc = bb3[j];
        #pragma unroll
        for (int k = 0; k < 32; ++k) acc += t2[k] * w3[k * 16 + j];
        t3[j] = (acc > 0.f) ? acc : expm1f(acc);
    }
    float o0 = bb4[0], o1 = bb4[1];
    #pragma unroll
    for (int k = 0; k < 16; ++k) {
        o0 += t3[k] * w4[k * 2 + 0];
        o1 += t3[k] * w4[k * 2 + 1];
    }
    out[(size_t)n * 2 + 0] = o0;
    out[(size_t)n * 2 + 1] = o1;
}

// ---------------------------------------------------------------------------
extern "C" void kernel_launch(void* const* d_in, const int* in_sizes, int n_in,
                              void* d_out, int out_size, void* d_ws, size_t ws_size,
                              hipStream_t stream)
{
    const float* x    = (const float*)d_in[0];
    const int*   ei   = (const int*)d_in[1];
    const float* Wpre = (const float*)d_in[2];
    const float* g0   = (const float*)d_in[3];
    const float* b0   = (const float*)d_in[4];

    const int N = in_sizes[0] / 128;
    const int E = in_sizes[1] / 2;
    const float invN = 1.f / (float)N;

    float* ws      = (float*)d_ws;
    float* h       = ws;                      // N*64
    float* xr_arr  = h + (size_t)N * 64;      // N*64
    float* z       = xr_arr + (size_t)N * 64; // N*64
    float* stats   = z + (size_t)N * 64;      // 5*128
    int*   deg     = (int*)(stats + 5 * 128); // N
    int*   row_ptr = deg + N;                 // N+4 (padded for alignment)
    int*   cursor  = row_ptr + N + 4;         // N
    int*   part    = cursor + N;              // 256
    int*   col     = part + 256;              // E
    __hip_bfloat16* xlb = (__hip_bfloat16*)(col + E);  // N*64 bf16

    const int* srcs = ei;
    const int* dsts = ei + E;
    const int nb = (N + 2047) / 2048;

    // ---- CSR build ----
    hipMemsetAsync(deg, 0, (size_t)N * sizeof(int), stream);
    hipMemsetAsync(stats, 0, 5 * 128 * sizeof(float), stream);
    hist_kernel<<<(E + 255) / 256, 256, 0, stream>>>(dsts, deg, E);
    scan_partials_kernel<<<nb, 256, 0, stream>>>(deg, part, N);
    scan_scan_kernel<<<1, 256, 0, stream>>>(part, nb);
    scan_final_kernel<<<nb, 256, 0, stream>>>(deg, part, row_ptr, cursor, N, E);
    scatter_kernel<<<(E + 255) / 256, 256, 0, stream>>>(srcs, dsts, cursor, col, E);

    // ---- pre-layer: z = x @ Wpre ; stats0 ----
    bn_gemm_kernel<128, 64, 16><<<(N + 15) / 16, 256, 0, stream>>>(
        x, Wpre, nullptr, z, nullptr, nullptr, nullptr, nullptr, nullptr, nullptr,
        N, invN);
    stats_kernel<<<1024, 256, 0, stream>>>(z, stats, N);

    // ---- 4 GATv2 layers ----
    for (int l = 0; l < 4; ++l) {
        const float* Wl  = (const float*)d_in[5 + 5 * l + 0];
        const float* Wr  = (const float*)d_in[5 + 5 * l + 1];
        const float* att = (const float*)d_in[5 + 5 * l + 2];
        const float* gp = (l == 0) ? g0 : (const float*)d_in[5 + 5 * (l - 1) + 3];
        const float* bp = (l == 0) ? b0 : (const float*)d_in[5 + 5 * (l - 1) + 4];
        float* statsp = stats + 128 * l;

        bn_gemm_kernel<64, 128, 16><<<(N + 15) / 16, 256, 0, stream>>>(
            z, Wl, Wr, nullptr, xlb, xr_arr, statsp, gp, bp, h, N, invN);
        gat_node_kernel<<<2560, 256, 0, stream>>>(
            row_ptr, col, xlb, xr_arr, att, h, z, stats + 128 * (l + 1), N);
    }

    // ---- MLP head (BN4 fused) ----
    const float* g4  = (const float*)d_in[23];
    const float* b4  = (const float*)d_in[24];
    const float* Wp1 = (const float*)d_in[25]; const float* bp1 = (const float*)d_in[26];
    const float* Wp2 = (const float*)d_in[27]; const float* bp2 = (const float*)d_in[28];
    const float* Wp3 = (const float*)d_in[29]; const float* bp3 = (const float*)d_in[30];
    const float* Wp4 = (const float*)d_in[31]; const float* bp4 = (const float*)d_in[32];
    mlp_kernel<<<(N + 255) / 256, 256, 0, stream>>>(
        z, stats + 512, g4, b4, Wp1, bp1, Wp2, bp2, Wp3, bp3, Wp4, bp4,
        (float*)d_out, N, invN);
}

// Round 6
// 655.863 us; speedup vs baseline: 1.3871x; 1.1966x over previous
//
#include <hip/hip_runtime.h>
#include <hip/hip_bf16.h>
#include <cmath>

__device__ inline void unpack_bf2(unsigned int u, float& lo, float& hi) {
    union { unsigned int i; float f; } a, b;
    a.i = u << 16; b.i = u & 0xffff0000u;
    lo = a.f; hi = b.f;
}
__device__ inline unsigned short bf16_bits(float x) {
    __hip_bfloat16 v = __float2bfloat16(x);
    return *reinterpret_cast<unsigned short*>(&v);
}

// ---------------------------------------------------------------------------
// Fused BN(+ELU) + GEMM. A[N,K] -> act -> @ [B0|B1] [K,M].
// If C != null: write fp32 C[N,M] (pre-layer).
// Else: write cols 0..63 as bf16 to xlb[N,64], cols 64..127 as f32 to xr[N,64].
// When stats != null, act = elu(bn(...)) and act(A) also written to hout.
// ---------------------------------------------------------------------------
template<int K, int M, int ROWS>
__global__ __launch_bounds__(256)
void bn_gemm_kernel(const float* __restrict__ A, const float* __restrict__ B0,
                    const float* __restrict__ B1, float* __restrict__ C,
                    __hip_bfloat16* __restrict__ xlb, float* __restrict__ xr_arr,
                    const float* __restrict__ stats, const float* __restrict__ g,
                    const float* __restrict__ b, float* __restrict__ hout,
                    int N, float invN)
{
    constexpr int TM = ROWS * M / 256;
    __shared__ float Bs[K * M];
    __shared__ float As[ROWS * (K + 1)];
    __shared__ float sm[K], sv[K], sg[K], sb[K];
    if (stats != nullptr && threadIdx.x < K) {
        int f = threadIdx.x;
        float m   = stats[f] * invN;
        float var = stats[K + f] * invN - m * m;
        sm[f] = m;
        sv[f] = rsqrtf(var + 1e-5f);
        sg[f] = g[f];
        sb[f] = b[f];
    }
    for (int i = threadIdx.x; i < K * M; i += 256) {
        float v;
        if (B1 != nullptr) {
            int k = i / M, m = i - k * M;
            v = (m < M / 2) ? B0[k * (M / 2) + m] : B1[k * (M / 2) + (m - M / 2)];
        } else {
            v = B0[i];
        }
        Bs[i] = v;
    }
    __syncthreads();
    int row0 = blockIdx.x * ROWS;
    for (int i = threadIdx.x; i < ROWS * K; i += 256) {
        int rr = i / K, kk = i - rr * K;
        int r = row0 + rr;
        float v = (r < N) ? A[(size_t)r * K + kk] : 0.f;
        if (stats != nullptr) {
            float t = sg[kk] * ((v - sm[kk]) * sv[kk]) + sb[kk];
            v = (t > 0.f) ? t : expm1f(t);
            if (r < N) hout[(size_t)r * K + kk] = v;
        }
        As[rr * (K + 1) + kk] = v;
    }
    __syncthreads();
    int r  = threadIdx.x / (M / TM);
    int m0 = (threadIdx.x % (M / TM)) * TM;
    int row = row0 + r;
    float acc[TM];
    #pragma unroll
    for (int i = 0; i < TM; ++i) acc[i] = 0.f;
    const float* as = &As[r * (K + 1)];
    for (int k = 0; k < K; ++k) {
        float a = as[k];
        #pragma unroll
        for (int mm = 0; mm < TM; mm += 4) {
            float4 bv = *(const float4*)&Bs[k * M + m0 + mm];
            acc[mm + 0] = fmaf(a, bv.x, acc[mm + 0]);
            acc[mm + 1] = fmaf(a, bv.y, acc[mm + 1]);
            acc[mm + 2] = fmaf(a, bv.z, acc[mm + 2]);
            acc[mm + 3] = fmaf(a, bv.w, acc[mm + 3]);
        }
    }
    if (row >= N) return;
    if (C != nullptr) {
        #pragma unroll
        for (int mm = 0; mm < TM; mm += 4) {
            float4 o = make_float4(acc[mm], acc[mm + 1], acc[mm + 2], acc[mm + 3]);
            *(float4*)&C[(size_t)row * M + m0 + mm] = o;
        }
    } else {
        if (m0 < 64) {
            unsigned int u[TM / 2];
            #pragma unroll
            for (int i = 0; i < TM / 2; ++i)
                u[i] = (unsigned int)bf16_bits(acc[2 * i]) |
                       ((unsigned int)bf16_bits(acc[2 * i + 1]) << 16);
            *(uint4*)(xlb + (size_t)row * 64 + m0) =
                make_uint4(u[0], u[1], u[2], u[3]);
        } else {
            #pragma unroll
            for (int mm = 0; mm < TM; mm += 4) {
                float4 o = make_float4(acc[mm], acc[mm + 1], acc[mm + 2], acc[mm + 3]);
                *(float4*)&xr_arr[(size_t)row * 64 + (m0 - 64) + mm] = o;
            }
        }
    }
}

// ---------------------------------------------------------------------------
// CSR build v2: locality-aware two-level counting sort.
// Bins of 256 consecutive dst values (NB = ceil(N/256) <= 256).
// ---------------------------------------------------------------------------
__global__ __launch_bounds__(256)
void bin_hist_kernel(const int* __restrict__ dsts, int* __restrict__ binCnt, int E)
{
    __shared__ int lh[256];
    lh[threadIdx.x] = 0;
    __syncthreads();
    for (int e = blockIdx.x * 256 + threadIdx.x; e < E; e += gridDim.x * 256)
        atomicAdd(&lh[dsts[e] >> 8], 1);
    __syncthreads();
    if (lh[threadIdx.x] > 0) atomicAdd(&binCnt[threadIdx.x], lh[threadIdx.x]);
}

__global__ __launch_bounds__(256)
void bin_scan_kernel(const int* __restrict__ binCnt, int* __restrict__ binBase,
                     int* __restrict__ binCursor, int* __restrict__ row_ptr,
                     int N, int E)
{
    __shared__ int buf[256];
    int v = binCnt[threadIdx.x];
    buf[threadIdx.x] = v;
    __syncthreads();
    for (int off = 1; off < 256; off <<= 1) {
        int t = (threadIdx.x >= off) ? buf[threadIdx.x - off] : 0;
        __syncthreads();
        buf[threadIdx.x] += t;
        __syncthreads();
    }
    int excl = buf[threadIdx.x] - v;
    binBase[threadIdx.x] = excl;
    binCursor[threadIdx.x] = excl;
    if (threadIdx.x == 255) {
        binBase[256] = buf[255];
        row_ptr[N] = E;
    }
}

// Per-block LDS counting sort by bin + burst copy to bin segments.
#define SCHUNK 4096
__global__ __launch_bounds__(256)
void bin_scatter_kernel(const int* __restrict__ srcs, const int* __restrict__ dsts,
                        int* __restrict__ binCursor, int2* __restrict__ binned, int E)
{
    __shared__ int2 stg[SCHUNK];
    __shared__ int bcnt[256], bexcl[256], bcur[256], gbase[256], sbuf[256];
    int c0 = blockIdx.x * SCHUNK;
    int n = min(SCHUNK, E - c0);
    bcnt[threadIdx.x] = 0;
    __syncthreads();
    for (int k = 0; k < SCHUNK / 256; ++k) {
        int i = c0 + k * 256 + threadIdx.x;
        if (i < E) atomicAdd(&bcnt[dsts[i] >> 8], 1);
    }
    __syncthreads();
    int v = bcnt[threadIdx.x];
    sbuf[threadIdx.x] = v;
    __syncthreads();
    for (int off = 1; off < 256; off <<= 1) {
        int t = (threadIdx.x >= off) ? sbuf[threadIdx.x - off] : 0;
        __syncthreads();
        sbuf[threadIdx.x] += t;
        __syncthreads();
    }
    bexcl[threadIdx.x] = sbuf[threadIdx.x] - v;
    bcur[threadIdx.x]  = sbuf[threadIdx.x] - v;
    __syncthreads();
    for (int k = 0; k < SCHUNK / 256; ++k) {
        int i = c0 + k * 256 + threadIdx.x;
        if (i < E) {
            int s = srcs[i], d = dsts[i];
            int pos = atomicAdd(&bcur[d >> 8], 1);
            stg[pos] = make_int2(s, d);
        }
    }
    __syncthreads();
    // one global claim per (block,bin)
    gbase[threadIdx.x] = atomicAdd(&binCursor[threadIdx.x], bcnt[threadIdx.x]);
    __syncthreads();
    // coalesced copy-out: staged order is bin-sorted
    for (int i = threadIdx.x; i < n; i += 256) {
        int2 p = stg[i];
        int b = p.y >> 8;
        binned[gbase[b] + (i - bexcl[b])] = p;
    }
}

// One block per bin: fine counting sort within the bin's contiguous region.
__global__ __launch_bounds__(256)
void bin_finalize_kernel(const int2* __restrict__ binned, const int* __restrict__ binBase,
                         int* __restrict__ row_ptr, int* __restrict__ col, int N)
{
    __shared__ int cnt[256], excl[256], cur[256];
    int b = blockIdx.x;
    int beg = binBase[b], end = binBase[b + 1];
    cnt[threadIdx.x] = 0;
    __syncthreads();
    for (int i = beg + threadIdx.x; i < end; i += 256)
        atomicAdd(&cnt[binned[i].y & 255], 1);
    __syncthreads();
    int v = cnt[threadIdx.x];
    excl[threadIdx.x] = v;
    __syncthreads();
    for (int off = 1; off < 256; off <<= 1) {
        int t = (threadIdx.x >= off) ? excl[threadIdx.x - off] : 0;
        __syncthreads();
        excl[threadIdx.x] += t;
        __syncthreads();
    }
    int ex = excl[threadIdx.x] - v;
    int dstIdx = b * 256 + threadIdx.x;
    if (dstIdx < N) row_ptr[dstIdx] = beg + ex;
    cur[threadIdx.x] = ex;
    __syncthreads();
    for (int i = beg + threadIdx.x; i < end; i += 256) {
        int2 p = binned[i];
        int pos = atomicAdd(&cur[p.y & 255], 1);
        col[beg + pos] = p.x;
    }
}

// ---------------------------------------------------------------------------
// Node-centric GATv2, (edge,head)-per-lane. lane = eg*8+h.
// col loaded once per 64 edges + shfl-distributed; 16 edges/iter (2 rows/lane)
// with next-iter prefetch; hres/xr prefetched at node start.
// ---------------------------------------------------------------------------
__device__ inline uint4 ldrow(const __hip_bfloat16* __restrict__ xlb,
                              int colv, int slot, int h)
{
    int idx = __shfl(colv, slot);
    return *(const uint4*)(xlb + (size_t)idx * 64 + h * 8);
}

__global__ __launch_bounds__(256)
void gat_node_kernel(const int* __restrict__ row_ptr, const int* __restrict__ col,
                     const __hip_bfloat16* __restrict__ xlb,
                     const float* __restrict__ xr_arr, const float* __restrict__ att,
                     const float* __restrict__ hres, float* __restrict__ z,
                     float* __restrict__ stats, int N)
{
    int lane = threadIdx.x & 63;
    int wid  = threadIdx.x >> 6;
    int eg   = lane >> 3;
    int h    = lane & 7;
    float attv[8];
    {
        const float4* a4 = (const float4*)(att + h * 8);
        float4 a0 = a4[0], a1 = a4[1];
        attv[0]=a0.x; attv[1]=a0.y; attv[2]=a0.z; attv[3]=a0.w;
        attv[4]=a1.x; attv[5]=a1.y; attv[6]=a1.z; attv[7]=a1.w;
    }
    float fs[8], fs2[8];
    #pragma unroll
    for (int c = 0; c < 8; ++c) { fs[c] = 0.f; fs2[c] = 0.f; }

    for (int n = blockIdx.x * 4 + wid; n < N; n += gridDim.x * 4) {
        int beg = row_ptr[n], end = row_ptr[n + 1];
        float hv[8];
        if (eg == 0) {
            const float4* hr4 = (const float4*)(hres + (size_t)n * 64 + h * 8);
            float4 h0 = hr4[0], h1 = hr4[1];
            hv[0]=h0.x; hv[1]=h0.y; hv[2]=h0.z; hv[3]=h0.w;
            hv[4]=h1.x; hv[5]=h1.y; hv[6]=h1.z; hv[7]=h1.w;
        }
        float xr[8];
        {
            const float4* x4 = (const float4*)(xr_arr + (size_t)n * 64 + h * 8);
            float4 r0 = x4[0], r1 = x4[1];
            xr[0]=r0.x; xr[1]=r0.y; xr[2]=r0.z; xr[3]=r0.w;
            xr[4]=r1.x; xr[5]=r1.y; xr[6]=r1.z; xr[7]=r1.w;
        }
        float acc[8];
        #pragma unroll
        for (int c = 0; c < 8; ++c) acc[c] = 0.f;
        float den = 0.f;

        for (int gb = beg; gb < end; gb += 64) {
            int cnt = min(64, end - gb);
            int colv = col[gb + min(lane, cnt - 1)];
            int nck = (cnt + 15) >> 4;
            uint4 pA = ldrow(xlb, colv, min(eg, cnt - 1), h);
            uint4 pB = ldrow(xlb, colv, min(eg + 8, cnt - 1), h);
            for (int c = 0; c < nck; ++c) {
                uint4 nA = pA, nB = pB;
                if (c + 1 < nck) {
                    nA = ldrow(xlb, colv, min((c + 1) * 16 + eg,     cnt - 1), h);
                    nB = ldrow(xlb, colv, min((c + 1) * 16 + 8 + eg, cnt - 1), h);
                }
                int s0 = c * 16 + eg, s1 = s0 + 8;
                {
                    float xl[8];
                    unpack_bf2(pA.x, xl[0], xl[1]);
                    unpack_bf2(pA.y, xl[2], xl[3]);
                    unpack_bf2(pA.z, xl[4], xl[5]);
                    unpack_bf2(pA.w, xl[6], xl[7]);
                    float logit = 0.f;
                    #pragma unroll
                    for (int cc = 0; cc < 8; ++cc) {
                        float sum = xl[cc] + xr[cc];
                        float lr = fmaf(0.8f, fmaxf(sum, 0.f), 0.2f * sum);
                        logit = fmaf(lr, attv[cc], logit);
                    }
                    float ex = (s0 < cnt) ? __expf(logit) : 0.f;
                    #pragma unroll
                    for (int cc = 0; cc < 8; ++cc) acc[cc] = fmaf(ex, xl[cc], acc[cc]);
                    den += ex;
                }
                {
                    float xl[8];
                    unpack_bf2(pB.x, xl[0], xl[1]);
                    unpack_bf2(pB.y, xl[2], xl[3]);
                    unpack_bf2(pB.z, xl[4], xl[5]);
                    unpack_bf2(pB.w, xl[6], xl[7]);
                    float logit = 0.f;
                    #pragma unroll
                    for (int cc = 0; cc < 8; ++cc) {
                        float sum = xl[cc] + xr[cc];
                        float lr = fmaf(0.8f, fmaxf(sum, 0.f), 0.2f * sum);
                        logit = fmaf(lr, attv[cc], logit);
                    }
                    float ex = (s1 < cnt) ? __expf(logit) : 0.f;
                    #pragma unroll
                    for (int cc = 0; cc < 8; ++cc) acc[cc] = fmaf(ex, xl[cc], acc[cc]);
                    den += ex;
                }
                pA = nA; pB = nB;
            }
        }
        #pragma unroll
        for (int off = 8; off <= 32; off <<= 1) {
            den += __shfl_xor(den, off);
            #pragma unroll
            for (int c = 0; c < 8; ++c) acc[c] += __shfl_xor(acc[c], off);
        }
        if (eg == 0) {
            float inv = 1.f / (den + 1e-16f);
            float v[8];
            #pragma unroll
            for (int c = 0; c < 8; ++c) {
                v[c] = acc[c] * inv + hv[c];
                fs[c] += v[c];
                fs2[c] += v[c] * v[c];
            }
            float4* z4 = (float4*)(z + (size_t)n * 64 + h * 8);
            z4[0] = make_float4(v[0], v[1], v[2], v[3]);
            z4[1] = make_float4(v[4], v[5], v[6], v[7]);
        }
    }
    __shared__ float lstat[2][4][64];
    if (eg == 0) {
        #pragma unroll
        for (int c = 0; c < 8; ++c) {
            lstat[0][wid][h * 8 + c] = fs[c];
            lstat[1][wid][h * 8 + c] = fs2[c];
        }
    }
    __syncthreads();
    if (threadIdx.x < 128) {
        int which = threadIdx.x >> 6;
        int f = threadIdx.x & 63;
        float a = lstat[which][0][f] + lstat[which][1][f] +
                  lstat[which][2][f] + lstat[which][3][f];
        unsafeAtomicAdd(&stats[which * 64 + f], a);
    }
}

// ---------------------------------------------------------------------------
// BN-stats over a plain array (pre-layer only).
// ---------------------------------------------------------------------------
__global__ __launch_bounds__(256)
void stats_kernel(const float* __restrict__ y, float* __restrict__ stats, int N)
{
    int f  = threadIdx.x & 63;
    int rg = threadIdx.x >> 6;
    float s = 0.f, s2 = 0.f;
    for (int r = blockIdx.x * 4 + rg; r < N; r += gridDim.x * 4) {
        float v = y[(size_t)r * 64 + f];
        s += v;
        s2 += v * v;
    }
    __shared__ float ls[2][4][64];
    ls[0][rg][f] = s;
    ls[1][rg][f] = s2;
    __syncthreads();
    if (threadIdx.x < 128) {
        int which = threadIdx.x >> 6;
        float a = ls[which][0][f] + ls[which][1][f] + ls[which][2][f] + ls[which][3][f];
        unsafeAtomicAdd(&stats[which * 64 + f], a);
    }
}

// ---------------------------------------------------------------------------
// MLP head with fused BN+ELU on the input: 64->48->32->16->2.
// ---------------------------------------------------------------------------
__global__ __launch_bounds__(256)
void mlp_kernel(const float* __restrict__ z, const float* __restrict__ stats,
                const float* __restrict__ g, const float* __restrict__ b,
                const float* __restrict__ W1, const float* __restrict__ B1,
                const float* __restrict__ W2, const float* __restrict__ B2,
                const float* __restrict__ W3, const float* __restrict__ B3,
                const float* __restrict__ W4, const float* __restrict__ B4,
                float* __restrict__ out, int N, float invN)
{
    __shared__ float w1[64 * 48], w2[48 * 32], w3[32 * 16], w4[16 * 2];
    __shared__ float bb1[48], bb2[32], bb3[16], bb4[2];
    __shared__ float sm[64], sv[64], sg[64], sb[64];
    for (int i = threadIdx.x; i < 64 * 48; i += 256) w1[i] = W1[i];
    for (int i = threadIdx.x; i < 48 * 32; i += 256) w2[i] = W2[i];
    for (int i = threadIdx.x; i < 32 * 16; i += 256) w3[i] = W3[i];
    for (int i = threadIdx.x; i < 16 * 2;  i += 256) w4[i] = W4[i];
    if (threadIdx.x < 48) bb1[threadIdx.x] = B1[threadIdx.x];
    if (threadIdx.x < 32) bb2[threadIdx.x] = B2[threadIdx.x];
    if (threadIdx.x < 16) bb3[threadIdx.x] = B3[threadIdx.x];
    if (threadIdx.x < 2)  bb4[threadIdx.x] = B4[threadIdx.x];
    if (threadIdx.x >= 64 && threadIdx.x < 128) {
        int f = threadIdx.x - 64;
        float m   = stats[f] * invN;
        float var = stats[64 + f] * invN - m * m;
        sm[f] = m;
        sv[f] = rsqrtf(var + 1e-5f);
        sg[f] = g[f];
        sb[f] = b[f];
    }
    __syncthreads();
    int n = blockIdx.x * 256 + threadIdx.x;
    if (n >= N) return;
    float a[64];
    const float4* hp = (const float4*)(z + (size_t)n * 64);
    #pragma unroll
    for (int i = 0; i < 16; ++i) {
        float4 v = hp[i];
        a[4 * i] = v.x; a[4 * i + 1] = v.y; a[4 * i + 2] = v.z; a[4 * i + 3] = v.w;
    }
    #pragma unroll
    for (int k = 0; k < 64; ++k) {
        float t = sg[k] * ((a[k] - sm[k]) * sv[k]) + sb[k];
        a[k] = (t > 0.f) ? t : expm1f(t);
    }
    float t1[48];
    for (int j = 0; j < 48; ++j) {
        float acc = bb1[j];
        #pragma unroll
        for (int k = 0; k < 64; ++k) acc += a[k] * w1[k * 48 + j];
        t1[j] = (acc > 0.f) ? acc : expm1f(acc);
    }
    float t2[32];
    for (int j = 0; j < 32; ++j) {
        float acc = bb2[j];
        #pragma unroll
        for (int k = 0; k < 48; ++k) acc += t1[k] * w2[k * 32 + j];
        t2[j] = (acc > 0.f) ? acc : expm1f(acc);
    }
    float t3[16];
    for (int j = 0; j < 16; ++j) {
        float acc = bb3[j];
        #pragma unroll
        for (int k = 0; k < 32; ++k) acc += t2[k] * w3[k * 16 + j];
        t3[j] = (acc > 0.f) ? acc : expm1f(acc);
    }
    float o0 = bb4[0], o1 = bb4[1];
    #pragma unroll
    for (int k = 0; k < 16; ++k) {
        o0 += t3[k] * w4[k * 2 + 0];
        o1 += t3[k] * w4[k * 2 + 1];
    }
    out[(size_t)n * 2 + 0] = o0;
    out[(size_t)n * 2 + 1] = o1;
}

// ---------------------------------------------------------------------------
extern "C" void kernel_launch(void* const* d_in, const int* in_sizes, int n_in,
                              void* d_out, int out_size, void* d_ws, size_t ws_size,
                              hipStream_t stream)
{
    const float* x    = (const float*)d_in[0];
    const int*   ei   = (const int*)d_in[1];
    const float* Wpre = (const float*)d_in[2];
    const float* g0   = (const float*)d_in[3];
    const float* b0   = (const float*)d_in[4];

    const int N = in_sizes[0] / 128;
    const int E = in_sizes[1] / 2;
    const float invN = 1.f / (float)N;
    const int NB = (N + 255) >> 8;   // bins of 256 dst values, NB <= 256

    float* ws      = (float*)d_ws;
    float* h       = ws;                       // N*64  (aliased: binned pairs E*int2)
    float* xr_arr  = h + (size_t)N * 64;       // N*64
    float* z       = xr_arr + (size_t)N * 64;  // N*64
    float* stats   = z + (size_t)N * 64;       // 5*128
    int*   row_ptr = (int*)(stats + 5 * 128);  // N+4
    int*   col     = row_ptr + N + 4;          // E
    __hip_bfloat16* xlb = (__hip_bfloat16*)(col + E);    // N*64 bf16 (N*32 ints)
    int*   binCnt    = (int*)(xlb + (size_t)N * 64);     // 256
    int*   binBase   = binCnt + 256;                     // 257
    int*   binCursor = binBase + 260;                    // 256
    int2*  binned    = (int2*)h;   // E pairs, 9.6MB <= N*64*4B; dead before h written

    const int* srcs = ei;
    const int* dsts = ei + E;

    // ---- CSR build (two-level counting sort, write-local) ----
    hipMemsetAsync(binCnt, 0, 256 * sizeof(int), stream);
    hipMemsetAsync(stats, 0, 5 * 128 * sizeof(float), stream);
    bin_hist_kernel<<<256, 256, 0, stream>>>(dsts, binCnt, E);
    bin_scan_kernel<<<1, 256, 0, stream>>>(binCnt, binBase, binCursor, row_ptr, N, E);
    bin_scatter_kernel<<<(E + SCHUNK - 1) / SCHUNK, 256, 0, stream>>>(
        srcs, dsts, binCursor, binned, E);
    bin_finalize_kernel<<<NB, 256, 0, stream>>>(binned, binBase, row_ptr, col, N);

    // ---- pre-layer: z = x @ Wpre ; stats0 ----
    bn_gemm_kernel<128, 64, 16><<<(N + 15) / 16, 256, 0, stream>>>(
        x, Wpre, nullptr, z, nullptr, nullptr, nullptr, nullptr, nullptr, nullptr,
        N, invN);
    stats_kernel<<<1024, 256, 0, stream>>>(z, stats, N);

    // ---- 4 GATv2 layers ----
    for (int l = 0; l < 4; ++l) {
        const float* Wl  = (const float*)d_in[5 + 5 * l + 0];
        const float* Wr  = (const float*)d_in[5 + 5 * l + 1];
        const float* att = (const float*)d_in[5 + 5 * l + 2];
        const float* gp = (l == 0) ? g0 : (const float*)d_in[5 + 5 * (l - 1) + 3];
        const float* bp = (l == 0) ? b0 : (const float*)d_in[5 + 5 * (l - 1) + 4];
        float* statsp = stats + 128 * l;

        bn_gemm_kernel<64, 128, 16><<<(N + 15) / 16, 256, 0, stream>>>(
            z, Wl, Wr, nullptr, xlb, xr_arr, statsp, gp, bp, h, N, invN);
        gat_node_kernel<<<2560, 256, 0, stream>>>(
            row_ptr, col, xlb, xr_arr, att, h, z, stats + 128 * (l + 1), N);
    }

    // ---- MLP head (BN4 fused) ----
    const float* g4  = (const float*)d_in[23];
    const float* b4  = (const float*)d_in[24];
    const float* Wp1 = (const float*)d_in[25]; const float* bp1 = (const float*)d_in[26];
    const float* Wp2 = (const float*)d_in[27]; const float* bp2 = (const float*)d_in[28];
    const float* Wp3 = (const float*)d_in[29]; const float* bp3 = (const float*)d_in[30];
    const float* Wp4 = (const float*)d_in[31]; const float* bp4 = (const float*)d_in[32];
    mlp_kernel<<<(N + 255) / 256, 256, 0, stream>>>(
        z, stats + 512, g4, b4, Wp1, bp1, Wp2, bp2, Wp3, bp3, Wp4, bp4,
        (float*)d_out, N, invN);
}